// Round 14
// baseline (114.530 us; speedup 1.0000x reference)
//
#include <hip/hip_runtime.h>
#include <hip/hip_bf16.h>

// StyledConv: B=8, Cin=Cout=64, H=W=256, S=512, K=3
#define BB   8
#define CC   64
#define HH   256
#define WW   256
#define SS   512
#define HW   (HH*WW)

#define LIN_SCALE  0.044194173824159216f   // 1/sqrt(512)
#define CONV_SCALE 0.041666666666666664f   // 1/24
#define LRELU      0.2f
#define GAIN       1.4142135623730951f

// tile: 8 rows x 32 cols, all 64 co, all 64 ci; 8 tiles per persistent block
#define TY 8
#define TX 32
#define LY (TY + 2)   // 10
#define LX (TX + 2)   // 34
#define XSE (8 * LY * LX * 8)       // 21760 elems per xs buffer
#define WLE (9 * 8 * 64 * 8)        // 36864 elems weights

typedef __attribute__((ext_vector_type(8)))  short short8;     // A/B frag (8 bf16)
typedef __attribute__((ext_vector_type(16))) float floatx16;   // 32x32 C/D frag

static __device__ __forceinline__ unsigned short f2bf(float f) {
    unsigned u = __float_as_uint(f);
    u += 0x7FFF + ((u >> 16) & 1);          // RNE (inputs finite)
    return (unsigned short)(u >> 16);
}

// packed f32x2 -> bf16x2 (v_cvt_pk_bf16_f32): low = a, high = b
static __device__ __forceinline__ unsigned pk2(float a, float b) {
    __hip_bfloat162 h = __float22bfloat162_rn(make_float2(a, b));
    return *(unsigned*)&h;
}

#define VC(vv,kk) ((kk)==0?(vv).x:((kk)==1?(vv).y:((kk)==2?(vv).z:(vv).w)))

// ---------------- Kernel A ----------------
__global__ void mod_kernel(const float* __restrict__ style,
                           const float* __restrict__ mod_w,
                           const float* __restrict__ mod_b,
                           float* __restrict__ s_out) {
    __shared__ float part[256];
    int b = blockIdx.x;
    int t = threadIdx.x;
    int ci = t & 63, kp = t >> 6;
    const float* st = style + b * SS + kp * 128;
    float acc = 0.f;
    for (int k = 0; k < 128; ++k)
        acc = fmaf(st[k], mod_w[(kp * 128 + k) * CC + ci], acc);
    part[t] = acc;
    __syncthreads();
    if (t < 64) {
        float v = part[t] + part[t + 64] + part[t + 128] + part[t + 192];
        s_out[b * CC + t] = v * LIN_SCALE + mod_b[t];
    }
}

// ---------------- Kernel B: weights -> wbf[b][ko 9][g 8][co 64][j 8] ----------------
__global__ void wmod_kernel(const float* __restrict__ weight,
                            const float* __restrict__ s_in,
                            unsigned short* __restrict__ wbf) {
    int bc = blockIdx.x;                // b*64 + co
    int b = bc >> 6, co = bc & 63;
    int ci = threadIdx.x;               // one wave
    float wv[9];
    float sv = s_in[b * CC + ci] * CONV_SCALE;
    float sum = 0.f;
    const float* wp = weight + (co * CC + ci) * 9;
#pragma unroll
    for (int k = 0; k < 9; ++k) {
        wv[k] = wp[k] * sv;
        sum = fmaf(wv[k], wv[k], sum);
    }
#pragma unroll
    for (int off = 32; off; off >>= 1)
        sum += __shfl_xor(sum, off);
    float demod = rsqrtf(sum + 1e-8f);
    int g = ci >> 3, j = ci & 7;
#pragma unroll
    for (int ko = 0; ko < 9; ++ko) {
        size_t idx = ((((size_t)b * 9 + ko) * 8 + g) * 64 + co) * 8 + j;
        wbf[idx] = f2bf(wv[ko] * demod);
    }
}

// ---------------- Kernel C: persistent implicit-GEMM conv, MFMA 32x32x16 bf16
// 256 blocks (1/CU), 256 thr (4 waves). Block owns 8 stacked 8x32 tiles.
// Weights: all 9 taps resident in wlds (72 KB, staged once).
// x: double-buffered xs (2 x 42.5 KB). Per tile: issue reg-staged loads for
// tile t+1 -> compute tile t (pure LDS+MFMA) -> vmcnt+convert+ds_write -> barrier.
__global__ __launch_bounds__(256, 1) void conv_kernel(
        const float* __restrict__ x,
        const float* __restrict__ noise,
        const float* __restrict__ nwp,
        const float* __restrict__ bias,
        const unsigned short* __restrict__ wbf,
        float* __restrict__ out) {
    extern __shared__ unsigned short smem[];
    unsigned short* xsA  = smem;               // XSE elems
    unsigned short* xsB  = smem + XSE;         // XSE elems
    unsigned short* wlds = smem + 2 * XSE;     // WLE elems

    // bijective XCD swizzle over 256 blocks: XCD c -> image b=c
    const int lin  = blockIdx.x;               // 0..255
    const int lin2 = (lin & 7) * 32 + (lin >> 3);
    const int b   = lin2 >> 5;                 // 0..7
    const int rem = lin2 & 31;
    const int bx  = rem & 7;                   // 0..7
    const int sy  = rem >> 3;                  // 0..3  (strip of 8 tiles)
    const int x0t = bx * TX;

    const int t = threadIdx.x;
    const int lane = t & 63;
    const int wv = t >> 6;         // wave 0..3 -> row pair
    const int n31 = lane & 31;
    const int h   = lane >> 5;     // k-slice half

    const float nw = nwp[0];

    // ---- prologue: stage all 9 weight taps (4608 uint4)
    {
        const uint4* wsrc = (const uint4*)(wbf + (size_t)b * WLE);
        uint4* wdst = (uint4*)wlds;
#pragma unroll
        for (int i = 0; i < 18; ++i)
            wdst[t + i * 256] = wsrc[t + i * 256];
    }

    // ---- prologue: stage tile 0 into xsA
    float4 vreg[4][8];
    {
        const int y0n = sy * 64;   // tile 0 of strip
#pragma unroll
        for (int it = 0; it < 4; ++it) {
            int n = t + it * 256; n = n < 799 ? n : 799;
            int q = n % 10; int rest = n / 10;
            int yl = rest % 10; int g = rest / 10;
            int gy = y0n + yl - 1;
            int gx0 = x0t - 4 + q * 4;
            int gyc  = gy < 0 ? 0 : (gy > HH - 1 ? HH - 1 : gy);
            int gx0c = gx0 < 0 ? 0 : (gx0 > WW - 4 ? WW - 4 : gx0);
            const float* xp = x + ((size_t)b * CC + g * 8) * HW + (size_t)gyc * WW + gx0c;
#pragma unroll
            for (int j = 0; j < 8; ++j)
                vreg[it][j] = *(const float4*)(xp + (size_t)j * HW);
        }
#pragma unroll
        for (int it = 0; it < 4; ++it) {
            int n = t + it * 256; n = n < 799 ? n : 799;
            int q = n % 10; int rest = n / 10;
            int yl = rest % 10; int g = rest / 10;
            int gy = y0n + yl - 1;
            int gx0 = x0t - 4 + q * 4;
            bool rowok = (unsigned)gy < (unsigned)HH;
#pragma unroll
            for (int k = 0; k < 4; ++k) {
                int lx = 4 * q - 3 + k;
                if ((unsigned)lx < (unsigned)LX) {
                    bool ok = rowok && ((unsigned)(gx0 + k) < (unsigned)WW);
                    uint4 w;
                    w.x = ok ? pk2(VC(vreg[it][0], k), VC(vreg[it][1], k)) : 0u;
                    w.y = ok ? pk2(VC(vreg[it][2], k), VC(vreg[it][3], k)) : 0u;
                    w.z = ok ? pk2(VC(vreg[it][4], k), VC(vreg[it][5], k)) : 0u;
                    w.w = ok ? pk2(VC(vreg[it][6], k), VC(vreg[it][7], k)) : 0u;
                    *(uint4*)&xsA[((g * LY + yl) * LX + lx) * 8] = w;
                }
            }
        }
    }
    // prologue noise for tile 0
    float nzc0, nzc1;
    {
        int py0 = sy * 64 + wv * 2;
        nzc0 = noise[(size_t)b * HW + (size_t)py0 * WW + x0t + n31];
        nzc1 = noise[(size_t)b * HW + (size_t)(py0 + 1) * WW + x0t + n31];
    }
    __syncthreads();

    unsigned short* xcur = xsA;
    unsigned short* xnxt = xsB;

#pragma unroll 1
    for (int tt = 0; tt < 8; ++tt) {
        const int y0t = (sy * 8 + tt) * TY;
        float nzn0 = 0.f, nzn1 = 0.f;

        // ---- issue reg-staged loads for tile tt+1
        if (tt < 7) {
            const int y0n = y0t + TY;
#pragma unroll
            for (int it = 0; it < 4; ++it) {
                int n = t + it * 256; n = n < 799 ? n : 799;
                int q = n % 10; int rest = n / 10;
                int yl = rest % 10; int g = rest / 10;
                int gy = y0n + yl - 1;
                int gx0 = x0t - 4 + q * 4;
                int gyc  = gy < 0 ? 0 : (gy > HH - 1 ? HH - 1 : gy);
                int gx0c = gx0 < 0 ? 0 : (gx0 > WW - 4 ? WW - 4 : gx0);
                const float* xp = x + ((size_t)b * CC + g * 8) * HW + (size_t)gyc * WW + gx0c;
#pragma unroll
                for (int j = 0; j < 8; ++j)
                    vreg[it][j] = *(const float4*)(xp + (size_t)j * HW);
            }
            int pyn = y0n + wv * 2;
            nzn0 = noise[(size_t)b * HW + (size_t)pyn * WW + x0t + n31];
            nzn1 = noise[(size_t)b * HW + (size_t)(pyn + 1) * WW + x0t + n31];
        }
        __builtin_amdgcn_sched_barrier(0);   // loads stay above compute

        // ---- compute tile tt (pure LDS + MFMA)
        floatx16 acc[2][2];
        acc[0][0] = (floatx16)0.f; acc[0][1] = (floatx16)0.f;
        acc[1][0] = (floatx16)0.f; acc[1][1] = (floatx16)0.f;

#pragma unroll
        for (int ko = 0; ko < 9; ++ko) {
            const int kh = ko / 3, kw = ko % 3;
#pragma unroll
            for (int kc = 0; kc < 4; ++kc) {
                const int g = kc * 2 + h;
                short8 av0 = *(const short8*)&wlds[((ko * 8 + g) * 64 + n31) * 8];
                short8 av1 = *(const short8*)&wlds[((ko * 8 + g) * 64 + 32 + n31) * 8];
#pragma unroll
                for (int rl = 0; rl < 2; ++rl) {
                    int ys = wv * 2 + rl + kh;
                    short8 bv = *(const short8*)&xcur[((g * LY + ys) * LX + kw + n31) * 8];
                    acc[rl][0] = __builtin_amdgcn_mfma_f32_32x32x16_bf16(
                        av0, bv, acc[rl][0], 0, 0, 0);
                    acc[rl][1] = __builtin_amdgcn_mfma_f32_32x32x16_bf16(
                        av1, bv, acc[rl][1], 0, 0, 0);
                }
            }
        }
        __builtin_amdgcn_sched_barrier(0);   // converts stay below compute

        // ---- convert + ds_write tile tt+1 (waits vmcnt internally)
        if (tt < 7) {
            const int y0n = y0t + TY;
#pragma unroll
            for (int it = 0; it < 4; ++it) {
                int n = t + it * 256; n = n < 799 ? n : 799;
                int q = n % 10; int rest = n / 10;
                int yl = rest % 10; int g = rest / 10;
                int gy = y0n + yl - 1;
                int gx0 = x0t - 4 + q * 4;
                bool rowok = (unsigned)gy < (unsigned)HH;
#pragma unroll
                for (int k = 0; k < 4; ++k) {
                    int lx = 4 * q - 3 + k;
                    if ((unsigned)lx < (unsigned)LX) {
                        bool ok = rowok && ((unsigned)(gx0 + k) < (unsigned)WW);
                        uint4 w;
                        w.x = ok ? pk2(VC(vreg[it][0], k), VC(vreg[it][1], k)) : 0u;
                        w.y = ok ? pk2(VC(vreg[it][2], k), VC(vreg[it][3], k)) : 0u;
                        w.z = ok ? pk2(VC(vreg[it][4], k), VC(vreg[it][5], k)) : 0u;
                        w.w = ok ? pk2(VC(vreg[it][6], k), VC(vreg[it][7], k)) : 0u;
                        *(uint4*)&xnxt[((g * LY + yl) * LX + lx) * 8] = w;
                    }
                }
            }
        }

        // ---- epilogue tile tt
        {
            float nz0 = nw * nzc0, nz1 = nw * nzc1;
#pragma unroll
            for (int rl = 0; rl < 2; ++rl) {
                int py = y0t + wv * 2 + rl;
                float nz = rl ? nz1 : nz0;
#pragma unroll
                for (int reg = 0; reg < 16; ++reg) {
                    int cr = (reg & 3) + 8 * (reg >> 2) + 4 * h;
                    float v0 = acc[rl][0][reg] + nz + bias[cr];
                    v0 = (v0 > 0.f ? v0 : LRELU * v0) * GAIN;
                    out[((size_t)b * CC + cr) * HW + (size_t)py * WW + x0t + n31] = v0;
                    float v1 = acc[rl][1][reg] + nz + bias[32 + cr];
                    v1 = (v1 > 0.f ? v1 : LRELU * v1) * GAIN;
                    out[((size_t)b * CC + 32 + cr) * HW + (size_t)py * WW + x0t + n31] = v1;
                }
            }
        }

        __syncthreads();
        // swap buffers / carry noise
        unsigned short* tmp = xcur; xcur = xnxt; xnxt = tmp;
        nzc0 = nzn0; nzc1 = nzn1;
    }
}

extern "C" void kernel_launch(void* const* d_in, const int* in_sizes, int n_in,
                              void* d_out, int out_size, void* d_ws, size_t ws_size,
                              hipStream_t stream) {
    const float* x       = (const float*)d_in[0];
    const float* style   = (const float*)d_in[1];
    const float* noise   = (const float*)d_in[2];
    const float* weight  = (const float*)d_in[3];
    const float* mod_w   = (const float*)d_in[4];
    const float* mod_b   = (const float*)d_in[5];
    const float* nw      = (const float*)d_in[6];
    const float* bias    = (const float*)d_in[7];
    float* out = (float*)d_out;

    float* s_buf          = (float*)d_ws;                          // 2 KB
    unsigned short* wbf   = (unsigned short*)((char*)d_ws + 4096); // 576 KB

    mod_kernel<<<dim3(BB), dim3(256), 0, stream>>>(style, mod_w, mod_b, s_buf);
    wmod_kernel<<<dim3(BB * CC), dim3(CC), 0, stream>>>(weight, s_buf, wbf);
    const int lds_bytes = (2 * XSE + WLE) * 2;   // 160768 B
    conv_kernel<<<dim3(256), dim3(256), lds_bytes, stream>>>(
        x, noise, nw, bias, wbf, out);
}

// Round 15
// 94.259 us; speedup vs baseline: 1.2150x; 1.2150x over previous
//
#include <hip/hip_runtime.h>
#include <hip/hip_bf16.h>

// StyledConv: B=8, Cin=Cout=64, H=W=256, S=512, K=3
#define BB   8
#define CC   64
#define HH   256
#define WW   256
#define SS   512
#define HW   (HH*WW)

#define LIN_SCALE  0.044194173824159216f   // 1/sqrt(512)
#define CONV_SCALE 0.041666666666666664f   // 1/24
#define LRELU      0.2f
#define GAIN       1.4142135623730951f

// conv tile: 8 rows x 32 cols out, all 64 co, all 64 ci staged once
#define TY 8
#define TX 32
#define LY (TY + 2)   // 10
#define LX (TX + 2)   // 34
#define WLE (9 * 8 * 64 * 8)        // weight elems per image

typedef __attribute__((ext_vector_type(8)))  short short8;     // A/B frag (8 bf16)
typedef __attribute__((ext_vector_type(16))) float floatx16;   // 32x32 C/D frag

static __device__ __forceinline__ unsigned short f2bf(float f) {
    unsigned u = __float_as_uint(f);
    u += 0x7FFF + ((u >> 16) & 1);          // RNE (inputs finite)
    return (unsigned short)(u >> 16);
}

// packed f32x2 -> bf16x2 (v_cvt_pk_bf16_f32): low = a, high = b
static __device__ __forceinline__ unsigned pk2(float a, float b) {
    __hip_bfloat162 h = __float22bfloat162_rn(make_float2(a, b));
    return *(unsigned*)&h;
}

#define VC(vv,kk) ((kk)==0?(vv).x:((kk)==1?(vv).y:((kk)==2?(vv).z:(vv).w)))

// ---------------- Kernel A ----------------
__global__ void mod_kernel(const float* __restrict__ style,
                           const float* __restrict__ mod_w,
                           const float* __restrict__ mod_b,
                           float* __restrict__ s_out) {
    __shared__ float part[256];
    int b = blockIdx.x;
    int t = threadIdx.x;
    int ci = t & 63, kp = t >> 6;
    const float* st = style + b * SS + kp * 128;
    float acc = 0.f;
    for (int k = 0; k < 128; ++k)
        acc = fmaf(st[k], mod_w[(kp * 128 + k) * CC + ci], acc);
    part[t] = acc;
    __syncthreads();
    if (t < 64) {
        float v = part[t] + part[t + 64] + part[t + 128] + part[t + 192];
        s_out[b * CC + t] = v * LIN_SCALE + mod_b[t];
    }
}

// ---------------- Kernel B: weights -> wbf[b][ko 9][g 8][co 64][j 8] ----------------
__global__ void wmod_kernel(const float* __restrict__ weight,
                            const float* __restrict__ s_in,
                            unsigned short* __restrict__ wbf) {
    int bc = blockIdx.x;                // b*64 + co
    int b = bc >> 6, co = bc & 63;
    int ci = threadIdx.x;               // one wave
    float wv[9];
    float sv = s_in[b * CC + ci] * CONV_SCALE;
    float sum = 0.f;
    const float* wp = weight + (co * CC + ci) * 9;
#pragma unroll
    for (int k = 0; k < 9; ++k) {
        wv[k] = wp[k] * sv;
        sum = fmaf(wv[k], wv[k], sum);
    }
#pragma unroll
    for (int off = 32; off; off >>= 1)
        sum += __shfl_xor(sum, off);
    float demod = rsqrtf(sum + 1e-8f);
    int g = ci >> 3, j = ci & 7;
#pragma unroll
    for (int ko = 0; ko < 9; ++ko) {
        size_t idx = ((((size_t)b * 9 + ko) * 8 + g) * 64 + co) * 8 + j;
        wbf[idx] = f2bf(wv[ko] * demod);
    }
}

// ---------------- Kernel C: implicit-GEMM conv, MFMA 32x32x16 bf16
// 256 thr (4 waves). Wave wv owns rows wv*2..wv*2+1 and ALL 64 co.
// A-frags from GLOBAL (L1/L2-resident wbf), depth-1 prefetch rotation.
// B-frags from xs LDS [g8][y10][x34][8ci] (contiguous conflict-free reads).
// LDS = xs only (43.5 KB) -> 3 blocks/CU, 12 waves. ONE barrier per block.
__global__ __launch_bounds__(256, 3) void conv_kernel(
        const float* __restrict__ x,
        const float* __restrict__ noise,
        const float* __restrict__ nwp,
        const float* __restrict__ bias,
        const unsigned short* __restrict__ wbf,
        float* __restrict__ out) {
    __shared__ unsigned short xs[8 * LY * LX * 8];   // 43520 B

    // bijective XCD swizzle: XCD c -> batch image b=c (256 blocks per image)
    const int lin  = blockIdx.x;                 // 0..2047
    const int lin2 = (lin & 7) * 256 + (lin >> 3);
    const int b   = lin2 >> 8;
    const int rem = lin2 & 255;
    const int by  = rem >> 3;      // 0..31
    const int bx  = rem & 7;       // 0..7
    const int x0t = bx * TX;
    const int y0t = by * TY;

    const int t = threadIdx.x;
    const int lane = t & 63;
    const int wv = t >> 6;         // wave 0..3 -> row pair
    const int n31 = lane & 31;
    const int h   = lane >> 5;     // k-slice half

    // ---- stage x: 800 tasks (g 8, yl 10, q 10; q fastest), branchless
#pragma unroll
    for (int it = 0; it < 4; ++it) {
        int n = t + it * 256;
        n = n < 799 ? n : 799;
        int q = n % 10;
        int rest = n / 10;          // 0..79
        int yl = rest % 10;
        int g  = rest / 10;         // 0..7
        int gy = y0t + yl - 1;      // -1..256
        int gx0 = x0t - 4 + q * 4;  // -4..256, 4-aligned
        bool rowok = (unsigned)gy < (unsigned)HH;
        int gyc  = gy < 0 ? 0 : (gy > HH - 1 ? HH - 1 : gy);
        int gx0c = gx0 < 0 ? 0 : (gx0 > WW - 4 ? WW - 4 : gx0);
        const float* xp = x + ((size_t)b * CC + g * 8) * HW + (size_t)gyc * WW + gx0c;
        float4 v[8];
#pragma unroll
        for (int j = 0; j < 8; ++j)
            v[j] = *(const float4*)(xp + (size_t)j * HW);
#pragma unroll
        for (int k = 0; k < 4; ++k) {
            int lx = 4 * q - 3 + k;
            if ((unsigned)lx < (unsigned)LX) {
                bool ok = rowok && ((unsigned)(gx0 + k) < (unsigned)WW);
                uint4 w;
                w.x = ok ? pk2(VC(v[0], k), VC(v[1], k)) : 0u;
                w.y = ok ? pk2(VC(v[2], k), VC(v[3], k)) : 0u;
                w.z = ok ? pk2(VC(v[4], k), VC(v[5], k)) : 0u;
                w.w = ok ? pk2(VC(v[6], k), VC(v[7], k)) : 0u;
                *(uint4*)&xs[((g * LY + yl) * LX + lx) * 8] = w;
            }
        }
    }
    __syncthreads();

    // ---- compute: A from global (prefetch depth 1), B from LDS
    const unsigned short* wb = wbf + (size_t)b * WLE;
#define ALOAD(ko, kc, m) \
    (*(const short8*)&wb[((((ko) * 8 + (kc) * 2 + h) * 64) + (m) * 32 + n31) * 8])

    floatx16 acc[2][2];
    acc[0][0] = (floatx16)0.f; acc[0][1] = (floatx16)0.f;
    acc[1][0] = (floatx16)0.f; acc[1][1] = (floatx16)0.f;

    short8 a0 = ALOAD(0, 0, 0);
    short8 a1 = ALOAD(0, 0, 1);

#pragma unroll
    for (int ko = 0; ko < 9; ++ko) {
        const int kh = ko / 3, kw = ko % 3;
#pragma unroll
        for (int kc = 0; kc < 4; ++kc) {
            short8 p0 = a0, p1 = a1;
            if (!(ko == 8 && kc == 3)) {
                int nko = (kc == 3) ? ko + 1 : ko;
                int nkc = (kc == 3) ? 0 : kc + 1;
                p0 = ALOAD(nko, nkc, 0);
                p1 = ALOAD(nko, nkc, 1);
            }
            const int g = kc * 2 + h;
#pragma unroll
            for (int rl = 0; rl < 2; ++rl) {
                int ys = wv * 2 + rl + kh;
                short8 bv = *(const short8*)&xs[((g * LY + ys) * LX + kw + n31) * 8];
                acc[rl][0] = __builtin_amdgcn_mfma_f32_32x32x16_bf16(
                    a0, bv, acc[rl][0], 0, 0, 0);
                acc[rl][1] = __builtin_amdgcn_mfma_f32_32x32x16_bf16(
                    a1, bv, acc[rl][1], 0, 0, 0);
            }
            a0 = p0; a1 = p1;
        }
    }
#undef ALOAD

    // ---- epilogue: noise + bias + leaky_relu * gain
    // D layout (32x32): col px = lane&31, row co32 = (reg&3) + 8*(reg>>2) + 4*h
    float nw = nwp[0];
#pragma unroll
    for (int rl = 0; rl < 2; ++rl) {
        int py = y0t + wv * 2 + rl;
        float nz = nw * noise[(size_t)b * HW + (size_t)py * WW + x0t + n31];
#pragma unroll
        for (int reg = 0; reg < 16; ++reg) {
            int cr = (reg & 3) + 8 * (reg >> 2) + 4 * h;
            float v0 = acc[rl][0][reg] + nz + bias[cr];
            v0 = (v0 > 0.f ? v0 : LRELU * v0) * GAIN;
            out[((size_t)b * CC + cr) * HW + (size_t)py * WW + x0t + n31] = v0;
            float v1 = acc[rl][1][reg] + nz + bias[32 + cr];
            v1 = (v1 > 0.f ? v1 : LRELU * v1) * GAIN;
            out[((size_t)b * CC + 32 + cr) * HW + (size_t)py * WW + x0t + n31] = v1;
        }
    }
}

extern "C" void kernel_launch(void* const* d_in, const int* in_sizes, int n_in,
                              void* d_out, int out_size, void* d_ws, size_t ws_size,
                              hipStream_t stream) {
    const float* x       = (const float*)d_in[0];
    const float* style   = (const float*)d_in[1];
    const float* noise   = (const float*)d_in[2];
    const float* weight  = (const float*)d_in[3];
    const float* mod_w   = (const float*)d_in[4];
    const float* mod_b   = (const float*)d_in[5];
    const float* nw      = (const float*)d_in[6];
    const float* bias    = (const float*)d_in[7];
    float* out = (float*)d_out;

    float* s_buf          = (float*)d_ws;                          // 2 KB
    unsigned short* wbf   = (unsigned short*)((char*)d_ws + 4096); // 576 KB

    mod_kernel<<<dim3(BB), dim3(256), 0, stream>>>(style, mod_w, mod_b, s_buf);
    wmod_kernel<<<dim3(BB * CC), dim3(CC), 0, stream>>>(weight, s_buf, wbf);
    conv_kernel<<<dim3((WW / TX) * (HH / TY) * BB), dim3(256), 0, stream>>>(
        x, noise, nw, bias, wbf, out);
}